// Round 4
// baseline (324.802 us; speedup 1.0000x reference)
//
#include <hip/hip_runtime.h>

// WindowAttention fused kernel for MI355X (gfx950) — v5.
// Shapes: B_=4096 windows, N=64 tokens, DIM=128, NH=4 heads, HD=32, nW=64.
// One block per window, one wave per head. bf16 MFMA 32x32x16, fp32 accum.
//
// v5 vs v4 (dispatch 146us): VALUBusy 28% (~41us) was the largest compute
// component; ~35% of it was the manual 5-op f2bf RNE converter (480 ops/
// thread across staging + Vt + PV epilogues). v5 uses native v_cvt_pk_bf16_f32
// via (__bf16) casts (same RNE), folds log2e into q-scale/q-bias/maskT/relT
// so softmax uses exp2f directly (saves 64 muls + shortens the exp chain),
// and reclaims 4 blocks/CU by reusing Xb as the O buffer (LDS 53248->35840,
// restoring the cheap post-QK barrier; (256,4) is safe at ~90 live regs).

typedef __bf16 bf16x8 __attribute__((ext_vector_type(8)));
typedef float f32x16 __attribute__((ext_vector_type(16)));

#define MFMA32(a, b, c) __builtin_amdgcn_mfma_f32_32x32x16_bf16(a, b, c, 0, 0, 0)
#define ATT_SCALE 0.17677669529663687f   // 32^-0.5
#define LOG2E     1.4426950408889634f
#define QSCL      (ATT_SCALE * LOG2E)    // folded: S' = S * log2e, exp -> exp2

__device__ __forceinline__ unsigned short bfu(float f) {
  union { __bf16 b; unsigned short u; } c;
  c.b = (__bf16)f;                        // v_cvt_pk_bf16_f32 (RNE), 1 op
  return c.u;
}

__device__ __forceinline__ unsigned pk2(float lo, float hi) {
  union { __bf16 h[2]; unsigned u; } t;
  t.h[0] = (__bf16)lo; t.h[1] = (__bf16)hi;  // packed cvt
  return t.u;
}

// C-regs of the T-form hold rows d=(r&3)+8*(r>>2)+4*hl at col=lane&31.
// A/B fragments need 8 consecutive k at this lane: lower 4-group from hl'=0
// values (lanes<32), upper from hl'=1 (lanes>=32) -> exchange via shfl_xor 32.
__device__ __forceinline__ void pairw(float l0, float l1, float h0, float h1,
                                      int hl, unsigned &wlo, unsigned &whi) {
  unsigned lo = pk2(l0, l1);
  unsigned hi = pk2(h0, h1);
  unsigned los = (unsigned)__shfl_xor((int)lo, 32);
  unsigned his = (unsigned)__shfl_xor((int)hi, 32);
  wlo = hl ? his : lo;   // lanes>=32 take partner's hi-group pair
  whi = hl ? hi : los;   // lanes<32 take partner's lo-group pair
}

// Build one K=16 fragment slot from 8 C-reg values (local k 0..15).
__device__ __forceinline__ bf16x8 frag8(float a0, float a1, float a2, float a3,
                                        float a4, float a5, float a6, float a7,
                                        int hl) {
  union { unsigned u[4]; bf16x8 v; } r;
  pairw(a0, a1, a4, a5, hl, r.u[0], r.u[2]);
  pairw(a2, a3, a6, a7, hl, r.u[1], r.u[3]);
  return r.v;
}

#define FRAG_LO(p) frag8(p[0], p[1], p[2], p[3], p[4], p[5], p[6], p[7], hl)
#define FRAG_HI(p) frag8(p[8], p[9], p[10], p[11], p[12], p[13], p[14], p[15], hl)

// ---- fused pre-kernel: maskT transpose + relT build + weight convert ----
// grid = 144 blocks x 256:
//   blocks [0,64): maskT[w][j][i] = mask[w][i][j] * LOG2E   (LDS transpose)
//   blocks [64,80): relT[h][j*64+i] = bias_table[ridx(i,j)*4+h] * LOG2E
//   blocks [80,144): wq/wp bf16 convert (q rows pre-scaled by QSCL)
__global__ __launch_bounds__(256) void prep(
    const float* __restrict__ mask, const float* __restrict__ bias_table,
    const float* __restrict__ qkv_w, const float* __restrict__ proj_w,
    float* __restrict__ maskT, float* __restrict__ relT,
    unsigned short* __restrict__ wq, unsigned short* __restrict__ wp) {
  const int blk = blockIdx.x;
  const int tid = threadIdx.x;
  if (blk < 64) {
    __shared__ float T[64][65];
    const float* mp = mask + (size_t)blk * 4096;
    #pragma unroll
    for (int rr = 0; rr < 16; ++rr) {
      int e = rr * 256 + tid;              // e = i*64 + j
      T[e >> 6][e & 63] = mp[e];           // coalesced read
    }
    __syncthreads();
    float* op = maskT + (size_t)blk * 4096;
    #pragma unroll
    for (int rr = 0; rr < 16; ++rr) {
      int e = rr * 256 + tid;              // e = j*64 + i
      op[e] = T[e & 63][e >> 6] * LOG2E;   // stride-65 LDS read: conflict-free
    }
  } else if (blk < 80) {
    int t0 = (blk - 64) * 256 + tid;       // 0..4095
    #pragma unroll
    for (int u = 0; u < 4; ++u) {
      int t = u * 4096 + t0;               // coalesced over relT
      int ji = t & 4095;
      int h = t >> 12;
      int j = ji >> 6, i = ji & 63;
      int ridx = ((i >> 3) - (j >> 3) + 7) * 15 + ((i & 7) - (j & 7) + 7);
      relT[t] = bias_table[ridx * 4 + h] * LOG2E;
    }
  } else {
    int t = ((blk - 80) * 256 + tid) * 4;  // 4 floats per thread
    if (t < 49152) {
      float4 v = *reinterpret_cast<const float4*>(qkv_w + t);
      float sc = (t < 16384) ? QSCL : 1.0f;   // q rows pre-scaled
      uint2 o;
      o.x = pk2(v.x * sc, v.y * sc);
      o.y = pk2(v.z * sc, v.w * sc);
      *reinterpret_cast<uint2*>(wq + t) = o;
    } else {
      int tp = t - 49152;
      float4 v = *reinterpret_cast<const float4*>(proj_w + tp);
      uint2 o;
      o.x = pk2(v.x, v.y);
      o.y = pk2(v.z, v.w);
      *reinterpret_cast<uint2*>(wp + tp) = o;
    }
  }
}

// ---- fused window attention ----
__global__ __launch_bounds__(256, 4) void window_attn(
    const float* __restrict__ x, const float* __restrict__ qkv_b,
    const float* __restrict__ proj_b, const unsigned short* __restrict__ wq,
    const unsigned short* __restrict__ wp, const float* __restrict__ maskT,
    const float* __restrict__ relT, float* __restrict__ out, int nW) {
  __shared__ unsigned short Xb[64][136];   // 17408 B; x bf16, reused as O
  __shared__ unsigned short Vt[4][32][72]; // 18432 B; vT[d][j] per head

  const int tid = threadIdx.x;
  const int h = tid >> 6;          // wave index == head
  const int lane = tid & 63;
  const int l31 = lane & 31;
  const int hl = lane >> 5;
  const int b = blockIdx.x;
  const int w = b % nW;

  // ---- stage x[b] (64x128 fp32) -> bf16 LDS, coalesced float4 + packed cvt ----
  const float* xb = x + (size_t)b * 8192;
  #pragma unroll
  for (int st = 0; st < 8; ++st) {
    int e = (st * 256 + tid) * 4;
    float4 v4 = *reinterpret_cast<const float4*>(xb + e);
    uint2 o;
    o.x = pk2(v4.x, v4.y);
    o.y = pk2(v4.z, v4.w);
    *reinterpret_cast<uint2*>(&Xb[e >> 7][e & 127]) = o;
  }
  __syncthreads();

  // ---- pass V: vT = Wv · X^T  (A = Wv rows, B = Xb token rows) ----
  {
    f32x16 av0, av1;
    #pragma unroll
    for (int q = 0; q < 16; ++q) { av0[q] = 0.0f; av1[q] = 0.0f; }
    const unsigned short* wvp = wq + (size_t)(256 + h * 32 + l31) * 128 + hl * 8;
    #pragma unroll
    for (int kt = 0; kt < 8; ++kt) {
      bf16x8 aw = *reinterpret_cast<const bf16x8*>(wvp + kt * 16);
      bf16x8 b0 = *reinterpret_cast<const bf16x8*>(&Xb[l31][kt * 16 + hl * 8]);
      bf16x8 b1 = *reinterpret_cast<const bf16x8*>(&Xb[32 + l31][kt * 16 + hl * 8]);
      av0 = MFMA32(aw, b0, av0);   // C[d][token 0..31]
      av1 = MFMA32(aw, b1, av1);   // C[d][token 32..63]
    }
    #pragma unroll
    for (int r = 0; r < 16; ++r) {
      int dr = (r & 3) + 8 * (r >> 2) + 4 * hl;
      float bv = qkv_b[256 + h * 32 + dr];
      Vt[h][dr][l31]      = bfu(av0[r] + bv);   // vT[d][j], wave-private
      Vt[h][dr][32 + l31] = bfu(av1[r] + bv);
    }
  }

  // ---- pass QK: qT = (QSCL·Wq)·X^T, kT = Wk·X^T ----
  bf16x8 qf[2][2], kf[2][2];
  {
    f32x16 aq[2], ak[2];
    #pragma unroll
    for (int t2 = 0; t2 < 2; ++t2)
      #pragma unroll
      for (int q = 0; q < 16; ++q) { aq[t2][q] = 0.0f; ak[t2][q] = 0.0f; }
    const unsigned short* wqp = wq + (size_t)(h * 32 + l31) * 128 + hl * 8;
    const unsigned short* wkp = wq + (size_t)(128 + h * 32 + l31) * 128 + hl * 8;
    #pragma unroll
    for (int kt = 0; kt < 8; ++kt) {
      bf16x8 b0 = *reinterpret_cast<const bf16x8*>(&Xb[l31][kt * 16 + hl * 8]);
      bf16x8 b1 = *reinterpret_cast<const bf16x8*>(&Xb[32 + l31][kt * 16 + hl * 8]);
      bf16x8 awq = *reinterpret_cast<const bf16x8*>(wqp + kt * 16);
      bf16x8 awk = *reinterpret_cast<const bf16x8*>(wkp + kt * 16);
      aq[0] = MFMA32(awq, b0, aq[0]);
      aq[1] = MFMA32(awq, b1, aq[1]);
      ak[0] = MFMA32(awk, b0, ak[0]);
      ak[1] = MFMA32(awk, b1, ak[1]);
    }
    __syncthreads();  // all Xb reads done -> Xb reusable as O

    // biases (q bias scaled to match pre-scaled Wq; includes log2e fold)
    #pragma unroll
    for (int r = 0; r < 16; ++r) {
      int dr = (r & 3) + 8 * (r >> 2) + 4 * hl;
      float bq = qkv_b[h * 32 + dr] * QSCL;
      float bk = qkv_b[128 + h * 32 + dr];
      aq[0][r] += bq; aq[1][r] += bq;
      ak[0][r] += bk; ak[1][r] += bk;
    }

    // in-register q/k fragments (kf first so ak dies before qf build peaks)
    #pragma unroll
    for (int t2 = 0; t2 < 2; ++t2) {
      kf[t2][0] = FRAG_LO(ak[t2]); kf[t2][1] = FRAG_HI(ak[t2]);
    }
    #pragma unroll
    for (int t2 = 0; t2 < 2; ++t2) {
      qf[t2][0] = FRAG_LO(aq[t2]); qf[t2][1] = FRAG_HI(aq[t2]);
    }
  }

  // ---- attention, split by token half it: rows i = l31 + 32*it ----
  // S' = S*log2e throughout; exp(S-m) == exp2(S'-m').
  const float* mkp = maskT + ((size_t)w << 12);  // maskT[w][j][i], L2-hot
  const float* rlp = relT + ((size_t)h << 12);   // relT[h][j][i], L1-hot
  #pragma unroll
  for (int it = 0; it < 2; ++it) {
    // S^T = k q^T with C initialized to combined (log2e-scaled) bias
    f32x16 s[2];
    #pragma unroll
    for (int mt = 0; mt < 2; ++mt)
      #pragma unroll
      for (int r = 0; r < 16; ++r) {
        int off = ((r & 3) + 8 * (r >> 2) + 4 * hl + 32 * mt) * 64 + 32 * it + l31;
        s[mt][r] = mkp[off] + rlp[off];
      }
    #pragma unroll
    for (int mt = 0; mt < 2; ++mt) {
      s[mt] = MFMA32(kf[mt][0], qf[it][0], s[mt]);
      s[mt] = MFMA32(kf[mt][1], qf[it][1], s[mt]);
    }

    // softmax over row i (this lane + partner lane^32 hold the 64 j's)
    float mx[8];
    #pragma unroll
    for (int r = 0; r < 8; ++r)
      mx[r] = fmaxf(fmaxf(s[0][r], s[0][r + 8]), fmaxf(s[1][r], s[1][r + 8]));
    mx[0] = fmaxf(mx[0], mx[4]); mx[1] = fmaxf(mx[1], mx[5]);
    mx[2] = fmaxf(mx[2], mx[6]); mx[3] = fmaxf(mx[3], mx[7]);
    float m = fmaxf(fmaxf(mx[0], mx[1]), fmaxf(mx[2], mx[3]));
    m = fmaxf(m, __shfl_xor(m, 32));
    #pragma unroll
    for (int mt = 0; mt < 2; ++mt)
      #pragma unroll
      for (int r = 0; r < 16; ++r)
        s[mt][r] = exp2f(s[mt][r] - m);        // unnormalized P
    float sm[8];
    #pragma unroll
    for (int r = 0; r < 8; ++r)
      sm[r] = (s[0][r] + s[0][r + 8]) + (s[1][r] + s[1][r + 8]);
    sm[0] += sm[4]; sm[1] += sm[5]; sm[2] += sm[6]; sm[3] += sm[7];
    float sum = (sm[0] + sm[1]) + (sm[2] + sm[3]);
    sum += __shfl_xor(sum, 32);
    const float rinv = __builtin_amdgcn_rcpf(sum);

    // in-register P^T fragments: pf[kt] = P^T[j=16kt+8hl+e][i=l31+32it]
    bf16x8 pf[4];
    pf[0] = FRAG_LO(s[0]); pf[1] = FRAG_HI(s[0]);
    pf[2] = FRAG_LO(s[1]); pf[3] = FRAG_HI(s[1]);

    // O^T = vT · P^T : lane holds O[i=l31+32it][d=(r&3)+8(r>>2)+4hl]
    f32x16 o;
    #pragma unroll
    for (int q = 0; q < 16; ++q) o[q] = 0.0f;
    #pragma unroll
    for (int kt = 0; kt < 4; ++kt) {
      bf16x8 aV = *reinterpret_cast<const bf16x8*>(&Vt[h][l31][kt * 16 + hl * 8]);
      o = MFMA32(aV, pf[kt], o);
    }
    #pragma unroll
    for (int r = 0; r < 16; ++r) {
      int dr = (r & 3) + 8 * (r >> 2) + 4 * hl;
      Xb[32 * it + l31][h * 32 + dr] = bfu(o[r] * rinv);  // Xb reused as O
    }
  }
  __syncthreads();  // O (all heads) ready

  // ---- out = O proj_w^T + proj_b : wave h computes out channels [h*32, h*32+32) ----
  {
    const int c = h * 32 + l31;
    const float pb = proj_b[c];
    const unsigned short* wrow = wp + (size_t)c * 128 + hl * 8;
    bf16x8 bfr[8];
    #pragma unroll
    for (int kt = 0; kt < 8; ++kt)
      bfr[kt] = *reinterpret_cast<const bf16x8*>(wrow + kt * 16);
    float* ob = out + (size_t)b * 8192;
    #pragma unroll
    for (int mt = 0; mt < 2; ++mt) {
      f32x16 acc;
      #pragma unroll
      for (int q = 0; q < 16; ++q) acc[q] = 0.0f;
      #pragma unroll
      for (int kt = 0; kt < 8; ++kt) {
        bf16x8 a = *reinterpret_cast<const bf16x8*>(&Xb[mt * 32 + l31][kt * 16 + hl * 8]);
        acc = MFMA32(a, bfr[kt], acc);
      }
      #pragma unroll
      for (int r = 0; r < 16; ++r) {
        int row = (r & 3) + 8 * (r >> 2) + 4 * hl + mt * 32;
        ob[row * 128 + c] = acc[r] + pb;
      }
    }
  }
}

extern "C" void kernel_launch(void* const* d_in, const int* in_sizes, int n_in,
                              void* d_out, int out_size, void* d_ws, size_t ws_size,
                              hipStream_t stream) {
  const float* x          = (const float*)d_in[0];
  const float* mask       = (const float*)d_in[1];
  const float* qkv_w      = (const float*)d_in[2];
  const float* qkv_b      = (const float*)d_in[3];
  const float* proj_w     = (const float*)d_in[4];
  const float* proj_b     = (const float*)d_in[5];
  const float* bias_table = (const float*)d_in[6];
  const int B_ = in_sizes[0] / 8192;   // 4096
  const int nW = in_sizes[1] / 4096;   // 64

  // workspace carve: wq bf16 (98304) | wp bf16 (32768) | maskT fp32 (1MB) | relT fp32 (64KB)
  unsigned short* wq = (unsigned short*)d_ws;
  unsigned short* wp = wq + 384 * 128;
  float* maskT = (float*)((char*)d_ws + 131072);
  float* relT  = (float*)((char*)d_ws + 131072 + (size_t)nW * 4096 * 4);

  prep<<<144, 256, 0, stream>>>(mask, bias_table, qkv_w, proj_w, maskT, relT, wq, wp);
  window_attn<<<B_, 256, 0, stream>>>(x, qkv_b, proj_b, wq, wp, maskT, relT, (float*)d_out, nW);
}

// Round 5
// 301.720 us; speedup vs baseline: 1.0765x; 1.0765x over previous
//
#include <hip/hip_runtime.h>

// WindowAttention fused kernel for MI355X (gfx950) — v6.
// Shapes: B_=4096 windows, N=64 tokens, DIM=128, NH=4 heads, HD=32, nW=64.
// One block per window, one wave per head. bf16 MFMA 32x32x16, fp32 accum.
//
// v6 = v4 structure + v5's good pieces. v5 regressed (164us vs v4's 146)
// because (256,4)'s 128-reg cap forced a 60-VGPR low-ILP schedule (absolute
// VALU-busy went UP) and the restored mid-barrier re-serialized QK->attn.
// v6: separate Ob (no mid barrier), (256,3) reg freedom, native packed bf16
// converts, log2e fold with __builtin_amdgcn_exp2f (single v_exp_f32, no
// libm denormal fixup), packed uint PV-epilogue writes, proj weights
// hoisted above the final barrier.

typedef __bf16 bf16x8 __attribute__((ext_vector_type(8)));
typedef float f32x16 __attribute__((ext_vector_type(16)));

#define MFMA32(a, b, c) __builtin_amdgcn_mfma_f32_32x32x16_bf16(a, b, c, 0, 0, 0)
#define ATT_SCALE 0.17677669529663687f   // 32^-0.5
#define LOG2E     1.4426950408889634f
#define QSCL      (ATT_SCALE * LOG2E)    // folded: S' = S * log2e, exp -> exp2

__device__ __forceinline__ unsigned short bfu(float f) {
  union { __bf16 b; unsigned short u; } c;
  c.b = (__bf16)f;                        // native cvt (RNE), 1 op
  return c.u;
}

__device__ __forceinline__ unsigned pk2(float lo, float hi) {
  union { __bf16 h[2]; unsigned u; } t;
  t.h[0] = (__bf16)lo; t.h[1] = (__bf16)hi;  // v_cvt_pk_bf16_f32
  return t.u;
}

// C-regs of the T-form hold rows d=(r&3)+8*(r>>2)+4*hl at col=lane&31.
// A/B fragments need 8 consecutive k at this lane: lower 4-group from hl'=0
// values (lanes<32), upper from hl'=1 (lanes>=32) -> exchange via shfl_xor 32.
__device__ __forceinline__ void pairw(float l0, float l1, float h0, float h1,
                                      int hl, unsigned &wlo, unsigned &whi) {
  unsigned lo = pk2(l0, l1);
  unsigned hi = pk2(h0, h1);
  unsigned los = (unsigned)__shfl_xor((int)lo, 32);
  unsigned his = (unsigned)__shfl_xor((int)hi, 32);
  wlo = hl ? his : lo;   // lanes>=32 take partner's hi-group pair
  whi = hl ? hi : los;   // lanes<32 take partner's lo-group pair
}

// Build one K=16 fragment slot from 8 C-reg values (local k 0..15).
__device__ __forceinline__ bf16x8 frag8(float a0, float a1, float a2, float a3,
                                        float a4, float a5, float a6, float a7,
                                        int hl) {
  union { unsigned u[4]; bf16x8 v; } r;
  pairw(a0, a1, a4, a5, hl, r.u[0], r.u[2]);
  pairw(a2, a3, a6, a7, hl, r.u[1], r.u[3]);
  return r.v;
}

#define FRAG_LO(p) frag8(p[0], p[1], p[2], p[3], p[4], p[5], p[6], p[7], hl)
#define FRAG_HI(p) frag8(p[8], p[9], p[10], p[11], p[12], p[13], p[14], p[15], hl)

// ---- fused pre-kernel: maskT transpose + relT build + weight convert ----
// grid = 144 blocks x 256:
//   blocks [0,64): maskT[w][j][i] = mask[w][i][j] * LOG2E   (LDS transpose)
//   blocks [64,80): relT[h][j*64+i] = bias_table[ridx(i,j)*4+h] * LOG2E
//   blocks [80,144): wq/wp bf16 convert (q rows pre-scaled by QSCL)
__global__ __launch_bounds__(256) void prep(
    const float* __restrict__ mask, const float* __restrict__ bias_table,
    const float* __restrict__ qkv_w, const float* __restrict__ proj_w,
    float* __restrict__ maskT, float* __restrict__ relT,
    unsigned short* __restrict__ wq, unsigned short* __restrict__ wp) {
  const int blk = blockIdx.x;
  const int tid = threadIdx.x;
  if (blk < 64) {
    __shared__ float T[64][65];
    const float* mp = mask + (size_t)blk * 4096;
    #pragma unroll
    for (int rr = 0; rr < 16; ++rr) {
      int e = rr * 256 + tid;              // e = i*64 + j
      T[e >> 6][e & 63] = mp[e];           // coalesced read
    }
    __syncthreads();
    float* op = maskT + (size_t)blk * 4096;
    #pragma unroll
    for (int rr = 0; rr < 16; ++rr) {
      int e = rr * 256 + tid;              // e = j*64 + i
      op[e] = T[e & 63][e >> 6] * LOG2E;   // stride-65 LDS read: conflict-free
    }
  } else if (blk < 80) {
    int t0 = (blk - 64) * 256 + tid;       // 0..4095
    #pragma unroll
    for (int u = 0; u < 4; ++u) {
      int t = u * 4096 + t0;               // coalesced over relT
      int ji = t & 4095;
      int h = t >> 12;
      int j = ji >> 6, i = ji & 63;
      int ridx = ((i >> 3) - (j >> 3) + 7) * 15 + ((i & 7) - (j & 7) + 7);
      relT[t] = bias_table[ridx * 4 + h] * LOG2E;
    }
  } else {
    int t = ((blk - 80) * 256 + tid) * 4;  // 4 floats per thread
    if (t < 49152) {
      float4 v = *reinterpret_cast<const float4*>(qkv_w + t);
      float sc = (t < 16384) ? QSCL : 1.0f;   // q rows pre-scaled
      uint2 o;
      o.x = pk2(v.x * sc, v.y * sc);
      o.y = pk2(v.z * sc, v.w * sc);
      *reinterpret_cast<uint2*>(wq + t) = o;
    } else {
      int tp = t - 49152;
      float4 v = *reinterpret_cast<const float4*>(proj_w + tp);
      uint2 o;
      o.x = pk2(v.x, v.y);
      o.y = pk2(v.z, v.w);
      *reinterpret_cast<uint2*>(wp + tp) = o;
    }
  }
}

// ---- fused window attention ----
__global__ __launch_bounds__(256, 3) void window_attn(
    const float* __restrict__ x, const float* __restrict__ qkv_b,
    const float* __restrict__ proj_b, const unsigned short* __restrict__ wq,
    const unsigned short* __restrict__ wp, const float* __restrict__ maskT,
    const float* __restrict__ relT, float* __restrict__ out, int nW) {
  __shared__ unsigned short Xb[64][136];   // 17408 B; x bf16
  __shared__ unsigned short Vt[4][32][72]; // 18432 B; vT[d][j] per head
  __shared__ unsigned short Ob[64][136];   // 17408 B; attention output O

  const int tid = threadIdx.x;
  const int h = tid >> 6;          // wave index == head
  const int lane = tid & 63;
  const int l31 = lane & 31;
  const int hl = lane >> 5;
  const int b = blockIdx.x;
  const int w = b % nW;

  // ---- stage x[b] (64x128 fp32) -> bf16 LDS, coalesced float4 + packed cvt ----
  const float* xb = x + (size_t)b * 8192;
  #pragma unroll
  for (int st = 0; st < 8; ++st) {
    int e = (st * 256 + tid) * 4;
    float4 v4 = *reinterpret_cast<const float4*>(xb + e);
    uint2 o;
    o.x = pk2(v4.x, v4.y);
    o.y = pk2(v4.z, v4.w);
    *reinterpret_cast<uint2*>(&Xb[e >> 7][e & 127]) = o;
  }
  __syncthreads();

  // ---- pass V: vT = Wv · X^T  (A = Wv rows, B = Xb token rows) ----
  {
    f32x16 av0, av1;
    #pragma unroll
    for (int q = 0; q < 16; ++q) { av0[q] = 0.0f; av1[q] = 0.0f; }
    const unsigned short* wvp = wq + (size_t)(256 + h * 32 + l31) * 128 + hl * 8;
    #pragma unroll
    for (int kt = 0; kt < 8; ++kt) {
      bf16x8 aw = *reinterpret_cast<const bf16x8*>(wvp + kt * 16);
      bf16x8 b0 = *reinterpret_cast<const bf16x8*>(&Xb[l31][kt * 16 + hl * 8]);
      bf16x8 b1 = *reinterpret_cast<const bf16x8*>(&Xb[32 + l31][kt * 16 + hl * 8]);
      av0 = MFMA32(aw, b0, av0);   // C[d][token 0..31]
      av1 = MFMA32(aw, b1, av1);   // C[d][token 32..63]
    }
    #pragma unroll
    for (int r = 0; r < 16; ++r) {
      int dr = (r & 3) + 8 * (r >> 2) + 4 * hl;
      float bv = qkv_b[256 + h * 32 + dr];
      Vt[h][dr][l31]      = bfu(av0[r] + bv);   // vT[d][j], wave-private
      Vt[h][dr][32 + l31] = bfu(av1[r] + bv);
    }
  }

  // ---- pass QK: qT = (QSCL·Wq)·X^T, kT = Wk·X^T ----
  bf16x8 qf[2][2], kf[2][2];
  {
    f32x16 aq[2], ak[2];
    #pragma unroll
    for (int t2 = 0; t2 < 2; ++t2)
      #pragma unroll
      for (int q = 0; q < 16; ++q) { aq[t2][q] = 0.0f; ak[t2][q] = 0.0f; }
    const unsigned short* wqp = wq + (size_t)(h * 32 + l31) * 128 + hl * 8;
    const unsigned short* wkp = wq + (size_t)(128 + h * 32 + l31) * 128 + hl * 8;
    #pragma unroll
    for (int kt = 0; kt < 8; ++kt) {
      bf16x8 b0 = *reinterpret_cast<const bf16x8*>(&Xb[l31][kt * 16 + hl * 8]);
      bf16x8 b1 = *reinterpret_cast<const bf16x8*>(&Xb[32 + l31][kt * 16 + hl * 8]);
      bf16x8 awq = *reinterpret_cast<const bf16x8*>(wqp + kt * 16);
      bf16x8 awk = *reinterpret_cast<const bf16x8*>(wkp + kt * 16);
      aq[0] = MFMA32(awq, b0, aq[0]);
      aq[1] = MFMA32(awq, b1, aq[1]);
      ak[0] = MFMA32(awk, b0, ak[0]);
      ak[1] = MFMA32(awk, b1, ak[1]);
    }

    // biases (q bias scaled to match pre-scaled Wq; includes log2e fold)
    #pragma unroll
    for (int r = 0; r < 16; ++r) {
      int dr = (r & 3) + 8 * (r >> 2) + 4 * hl;
      float bq = qkv_b[h * 32 + dr] * QSCL;
      float bk = qkv_b[128 + h * 32 + dr];
      aq[0][r] += bq; aq[1][r] += bq;
      ak[0][r] += bk; ak[1][r] += bk;
    }

    // in-register q/k fragments (kf first so ak dies before qf build peaks)
    #pragma unroll
    for (int t2 = 0; t2 < 2; ++t2) {
      kf[t2][0] = FRAG_LO(ak[t2]); kf[t2][1] = FRAG_HI(ak[t2]);
    }
    #pragma unroll
    for (int t2 = 0; t2 < 2; ++t2) {
      qf[t2][0] = FRAG_LO(aq[t2]); qf[t2][1] = FRAG_HI(aq[t2]);
    }
  }

  // ---- attention, split by token half it: rows i = l31 + 32*it ----
  // S' = S*log2e throughout; exp(S-m) == exp2(S'-m').
  const float* mkp = maskT + ((size_t)w << 12);  // maskT[w][j][i], L2-hot
  const float* rlp = relT + ((size_t)h << 12);   // relT[h][j][i], L1-hot
  #pragma unroll
  for (int it = 0; it < 2; ++it) {
    // S^T = k q^T with C initialized to combined (log2e-scaled) bias
    f32x16 s[2];
    #pragma unroll
    for (int mt = 0; mt < 2; ++mt)
      #pragma unroll
      for (int r = 0; r < 16; ++r) {
        int off = ((r & 3) + 8 * (r >> 2) + 4 * hl + 32 * mt) * 64 + 32 * it + l31;
        s[mt][r] = mkp[off] + rlp[off];
      }
    #pragma unroll
    for (int mt = 0; mt < 2; ++mt) {
      s[mt] = MFMA32(kf[mt][0], qf[it][0], s[mt]);
      s[mt] = MFMA32(kf[mt][1], qf[it][1], s[mt]);
    }

    // softmax over row i (this lane + partner lane^32 hold the 64 j's)
    float mx[8];
    #pragma unroll
    for (int r = 0; r < 8; ++r)
      mx[r] = fmaxf(fmaxf(s[0][r], s[0][r + 8]), fmaxf(s[1][r], s[1][r + 8]));
    mx[0] = fmaxf(mx[0], mx[4]); mx[1] = fmaxf(mx[1], mx[5]);
    mx[2] = fmaxf(mx[2], mx[6]); mx[3] = fmaxf(mx[3], mx[7]);
    float m = fmaxf(fmaxf(mx[0], mx[1]), fmaxf(mx[2], mx[3]));
    m = fmaxf(m, __shfl_xor(m, 32));
    #pragma unroll
    for (int mt = 0; mt < 2; ++mt)
      #pragma unroll
      for (int r = 0; r < 16; ++r)
        s[mt][r] = __builtin_amdgcn_exp2f(s[mt][r] - m);   // unnormalized P
    float sm[8];
    #pragma unroll
    for (int r = 0; r < 8; ++r)
      sm[r] = (s[0][r] + s[0][r + 8]) + (s[1][r] + s[1][r + 8]);
    sm[0] += sm[4]; sm[1] += sm[5]; sm[2] += sm[6]; sm[3] += sm[7];
    float sum = (sm[0] + sm[1]) + (sm[2] + sm[3]);
    sum += __shfl_xor(sum, 32);
    const float rinv = __builtin_amdgcn_rcpf(sum);

    // in-register P^T fragments: pf[kt] = P^T[j=16kt+8hl+e][i=l31+32it]
    bf16x8 pf[4];
    pf[0] = FRAG_LO(s[0]); pf[1] = FRAG_HI(s[0]);
    pf[2] = FRAG_LO(s[1]); pf[3] = FRAG_HI(s[1]);

    // O^T = vT · P^T : lane holds O[i=l31+32it][d=(r&3)+8(r>>2)+4hl]
    f32x16 o;
    #pragma unroll
    for (int q = 0; q < 16; ++q) o[q] = 0.0f;
    #pragma unroll
    for (int kt = 0; kt < 4; ++kt) {
      bf16x8 aV = *reinterpret_cast<const bf16x8*>(&Vt[h][l31][kt * 16 + hl * 8]);
      o = MFMA32(aV, pf[kt], o);
    }
    // packed epilogue: dr,dr+1 contiguous for (r even, r odd) pairs
    #pragma unroll
    for (int rp = 0; rp < 8; ++rp) {
      int r = rp * 2;
      int dr = (r & 3) + 8 * (r >> 2) + 4 * hl;
      unsigned pkd = pk2(o[r] * rinv, o[r + 1] * rinv);
      *reinterpret_cast<unsigned*>(&Ob[32 * it + l31][h * 32 + dr]) = pkd;
    }
  }

  // ---- proj weights/bias: hoist loads above the barrier (independent of Ob) ----
  const int c = h * 32 + l31;
  const float pb = proj_b[c];
  bf16x8 bfr[8];
  {
    const unsigned short* wrow = wp + (size_t)c * 128 + hl * 8;
    #pragma unroll
    for (int kt = 0; kt < 8; ++kt)
      bfr[kt] = *reinterpret_cast<const bf16x8*>(wrow + kt * 16);
  }
  __syncthreads();  // O (all heads) ready

  // ---- out = O proj_w^T + proj_b : wave h computes out channels [h*32, h*32+32) ----
  {
    float* ob = out + (size_t)b * 8192;
    #pragma unroll
    for (int mt = 0; mt < 2; ++mt) {
      f32x16 acc;
      #pragma unroll
      for (int q = 0; q < 16; ++q) acc[q] = 0.0f;
      #pragma unroll
      for (int kt = 0; kt < 8; ++kt) {
        bf16x8 a = *reinterpret_cast<const bf16x8*>(&Ob[mt * 32 + l31][kt * 16 + hl * 8]);
        acc = MFMA32(a, bfr[kt], acc);
      }
      #pragma unroll
      for (int r = 0; r < 16; ++r) {
        int row = (r & 3) + 8 * (r >> 2) + 4 * hl + mt * 32;
        ob[row * 128 + c] = acc[r] + pb;
      }
    }
  }
}

extern "C" void kernel_launch(void* const* d_in, const int* in_sizes, int n_in,
                              void* d_out, int out_size, void* d_ws, size_t ws_size,
                              hipStream_t stream) {
  const float* x          = (const float*)d_in[0];
  const float* mask       = (const float*)d_in[1];
  const float* qkv_w      = (const float*)d_in[2];
  const float* qkv_b      = (const float*)d_in[3];
  const float* proj_w     = (const float*)d_in[4];
  const float* proj_b     = (const float*)d_in[5];
  const float* bias_table = (const float*)d_in[6];
  const int B_ = in_sizes[0] / 8192;   // 4096
  const int nW = in_sizes[1] / 4096;   // 64

  // workspace carve: wq bf16 (98304) | wp bf16 (32768) | maskT fp32 (1MB) | relT fp32 (64KB)
  unsigned short* wq = (unsigned short*)d_ws;
  unsigned short* wp = wq + 384 * 128;
  float* maskT = (float*)((char*)d_ws + 131072);
  float* relT  = (float*)((char*)d_ws + 131072 + (size_t)nW * 4096 * 4);

  prep<<<144, 256, 0, stream>>>(mask, bias_table, qkv_w, proj_w, maskT, relT, wq, wp);
  window_attn<<<B_, 256, 0, stream>>>(x, qkv_b, proj_b, wq, wp, maskT, relT, (float*)d_out, nW);
}